// Round 2
// baseline (354.087 us; speedup 1.0000x reference)
//
#include <hip/hip_runtime.h>

#define NV 8192
#define NH 4096
#define TPB 256
#define HPB 32                     // h rows per block
#define HCH (NH / HPB)             // 128 h-chunks (gridDim.y)
#define ROW4 (NV / 4)              // 2048 float4 per row
#define VBLK (ROW4 / TPB)          // 8 blocks in x
#define NPART (VBLK * HCH)         // 1024 trace partials

typedef float f32x4 __attribute__((ext_vector_type(4)));  // native vec for nontemporal store

// output layout (flat float offsets, reference return order)
#define OFF_B   ((size_t)0)
#define OFF_WT  ((size_t)NV)
#define OFF_SIG ((size_t)NV + (size_t)NH * (size_t)NV)
#define OFF_MUH (OFF_SIG + 1)
#define OFF_VHD (OFF_MUH + NH)

__global__ __launch_bounds__(TPB) void init_k(
    const float* __restrict__ muvTE,
    const float* __restrict__ varh_diagTE,
    const float* __restrict__ muhTE,
    float* __restrict__ out)
{
    int i = blockIdx.x * TPB + threadIdx.x;     // grid covers NV
    if (i < NV) out[OFF_B + i] = muvTE[i];
    if (i < NH) {
        out[OFF_MUH + i] = muhTE[i];
        out[OFF_VHD + i] = varh_diagTE[i];
    }
}

__global__ __launch_bounds__(TPB) void main_k(
    const float4* __restrict__ varvhTE4,
    const float4* __restrict__ varvh4,
    const float* __restrict__ varh_diagTE,
    const float* __restrict__ varh_diag,
    const float* __restrict__ muh,
    const float* __restrict__ muhTE,
    float* __restrict__ out,
    float* __restrict__ tr_partial)
{
    __shared__ float4 coef_s[HPB];
    const int t  = threadIdx.x;
    const int h0 = blockIdx.y * HPB;

    // per-h coefficients: {inv, inv*muh, d*muh - inv*muhTE, d}
    if (t < HPB) {
        int h = h0 + t;
        float inv  = 1.0f / varh_diag[h];
        float vte  = varh_diagTE[h];
        float d    = inv * vte * inv;
        float m    = muh[h];
        coef_s[t] = make_float4(inv, inv * m, d * m - inv * muhTE[h], d);
    }
    __syncthreads();

    const int v4 = blockIdx.x * TPB + t;        // float4 column index
    f32x4* wt4 = (f32x4*)(out + OFF_WT);

    float bx = 0.f, by = 0.f, bz = 0.f, bw = 0.f;
    float tr = 0.f;

    #pragma unroll 4
    for (int hh = 0; hh < HPB; ++hh) {
        float4 c = coef_s[hh];
        size_t idx = (size_t)(h0 + hh) * ROW4 + (size_t)v4;
        float4 aTE = varvhTE4[idx];
        float4 a   = varvh4[idx];

        f32x4 w;
        w.x = c.x * aTE.x - c.w * a.x;
        w.y = c.x * aTE.y - c.w * a.y;
        w.z = c.x * aTE.z - c.w * a.z;
        w.w = c.x * aTE.w - c.w * a.w;
        __builtin_nontemporal_store(w, &wt4[idx]);

        bx += c.z * a.x - c.y * aTE.x;
        by += c.z * a.y - c.y * aTE.y;
        bz += c.z * a.z - c.y * aTE.z;
        bw += c.z * a.w - c.y * aTE.w;

        float dot = aTE.x * a.x + aTE.y * a.y + aTE.z * a.z + aTE.w * a.w;
        float sq  = a.x * a.x + a.y * a.y + a.z * a.z + a.w * a.w;
        tr += 2.0f * c.x * dot - c.w * sq;
    }

    // bTE partial sums -> device-scope float atomics (init_k wrote muvTE base)
    int v = v4 * 4;
    atomicAdd(&out[OFF_B + v + 0], bx);
    atomicAdd(&out[OFF_B + v + 1], by);
    atomicAdd(&out[OFF_B + v + 2], bz);
    atomicAdd(&out[OFF_B + v + 3], bw);

    // block-reduce trace partial: wave64 shuffle, then LDS across 4 waves
    for (int off = 32; off > 0; off >>= 1)
        tr += __shfl_down(tr, off);
    __shared__ float wsum[TPB / 64];
    if ((t & 63) == 0) wsum[t >> 6] = tr;
    __syncthreads();
    if (t == 0) {
        float s = wsum[0] + wsum[1] + wsum[2] + wsum[3];
        tr_partial[blockIdx.y * VBLK + blockIdx.x] = s;
    }
}

__global__ __launch_bounds__(TPB) void fin_k(
    const float* __restrict__ tr_partial,
    const float* __restrict__ varvbarTE,
    float* __restrict__ out)
{
    int t = threadIdx.x;
    float s = 0.f;
    for (int i = t; i < NPART; i += TPB) s += tr_partial[i];
    for (int off = 32; off > 0; off >>= 1)
        s += __shfl_down(s, off);
    __shared__ float wsum[TPB / 64];
    if ((t & 63) == 0) wsum[t >> 6] = s;
    __syncthreads();
    if (t == 0) {
        float tr = wsum[0] + wsum[1] + wsum[2] + wsum[3];
        out[OFF_SIG] = (varvbarTE[0] - tr) / (float)NV;
    }
}

extern "C" void kernel_launch(void* const* d_in, const int* in_sizes, int n_in,
                              void* d_out, int out_size, void* d_ws, size_t ws_size,
                              hipStream_t stream) {
    const float* muvTE       = (const float*)d_in[0];
    const float* varvhTE     = (const float*)d_in[1];
    const float* varh_diagTE = (const float*)d_in[2];
    const float* varh_diag   = (const float*)d_in[3];
    const float* muh         = (const float*)d_in[4];
    const float* varvh       = (const float*)d_in[5];
    const float* muhTE       = (const float*)d_in[6];
    const float* varvbarTE   = (const float*)d_in[7];
    float* out        = (float*)d_out;
    float* tr_partial = (float*)d_ws;   // NPART floats = 4 KB

    init_k<<<NV / TPB, TPB, 0, stream>>>(muvTE, varh_diagTE, muhTE, out);
    main_k<<<dim3(VBLK, HCH), TPB, 0, stream>>>(
        (const float4*)varvhTE, (const float4*)varvh,
        varh_diagTE, varh_diag, muh, muhTE, out, tr_partial);
    fin_k<<<1, TPB, 0, stream>>>(tr_partial, varvbarTE, out);
}